// Round 1
// baseline (2178.933 us; speedup 1.0000x reference)
//
#include <hip/hip_runtime.h>
#include <hip/hip_fp16.h>

#define NB 8
#define NC 256
#define NHW 1024
#define NI 8
#define NH 4
#define HD 64
#define EPS 1e-12f

// ---------------- K1: instance conv + softmax over instances ----------------
// grid (4 ntiles, 8 b), block 256. masks layout [i][b][n]
__global__ __launch_bounds__(256) void k_masks(
    const float* __restrict__ x, const float* __restrict__ w_inst,
    const float* __restrict__ b_inst, float* __restrict__ masks)
{
    __shared__ float w_s[NI][NC];
    int tid = threadIdx.x;
    for (int k = tid; k < NI*NC; k += 256) ((float*)w_s)[k] = w_inst[k];
    __syncthreads();
    int b = blockIdx.y;
    int n = blockIdx.x*256 + tid;
    const float* xp = x + ((size_t)b*NC)*NHW + n;
    float acc[NI];
#pragma unroll
    for (int i=0;i<NI;i++) acc[i] = b_inst[i];
    for (int c=0;c<NC;c++) {
        float xv = xp[(size_t)c*NHW];
#pragma unroll
        for (int i=0;i<NI;i++) acc[i] = fmaf(w_s[i][c], xv, acc[i]);
    }
    float m = acc[0];
#pragma unroll
    for (int i=1;i<NI;i++) m = fmaxf(m, acc[i]);
    float ssum = 0.f;
#pragma unroll
    for (int i=0;i<NI;i++){ acc[i] = __expf(acc[i]-m); ssum += acc[i]; }
    float inv = 1.0f/ssum;
#pragma unroll
    for (int i=0;i<NI;i++) masks[((size_t)i*NB + b)*NHW + n] = acc[i]*inv;
}

// ---------------- K2: fused Q/K/V GEMM for one instance ----------------
// grid (8 ntiles, 4 otiles, 8 b), block 256.
// q[o,n] = sum_c W[o,c] * x[b,c,n]*mask[n] + bias[o]
__global__ __launch_bounds__(256,2) void k_qkv(
    const float* __restrict__ x, const float* __restrict__ masks, int inst,
    const float* __restrict__ wq, const float* __restrict__ bq,
    const float* __restrict__ wk, const float* __restrict__ bk,
    const float* __restrict__ wv, const float* __restrict__ bv,
    float* __restrict__ Q, float* __restrict__ K, float* __restrict__ V)
{
    __shared__ __align__(16) float feat_s[32][128];   // [c-chunk][n]
    __shared__ __align__(16) float w_s[3][32][68];    // [mat][c-chunk][o] (transposed, stride 68 keeps 16B align)
    int tid = threadIdx.x;
    int b = blockIdx.z, ot = blockIdx.y, nt = blockIdx.x;
    int o0 = ot*64, n0 = nt*128;
    int og = tid >> 5;      // 0..7  -> o = og*8 + io
    int nl = tid & 31;      // 0..31 -> n = nl*4 + in
    int nn = tid & 127;     // staging column
    int ch = tid >> 7;      // staging row parity
    const float* mp = masks + ((size_t)inst*NB + b)*NHW + n0;
    const float* xb = x + ((size_t)b*NC)*NHW + n0;
    float mv = mp[nn];
    float acc[3][8][4] = {};
    for (int c0 = 0; c0 < NC; c0 += 32) {
        __syncthreads();
#pragma unroll
        for (int r=0;r<16;r++) {
            int cc = 2*r + ch;
            feat_s[cc][nn] = xb[(size_t)(c0+cc)*NHW + nn] * mv;
        }
        {
            int cw = tid & 31;
#pragma unroll
            for (int r=0;r<8;r++) {
                int oo = 8*r + og;
                size_t gi = (size_t)(o0+oo)*NC + c0 + cw;
                w_s[0][cw][oo] = wq[gi];
                w_s[1][cw][oo] = wk[gi];
                w_s[2][cw][oo] = wv[gi];
            }
        }
        __syncthreads();
#pragma unroll 4
        for (int c=0;c<32;c++) {
            float4 f4 = *(const float4*)&feat_s[c][nl*4];
            float f[4] = {f4.x, f4.y, f4.z, f4.w};
            float4 a0 = *(const float4*)&w_s[0][c][og*8];
            float4 a1 = *(const float4*)&w_s[0][c][og*8+4];
            float4 b0 = *(const float4*)&w_s[1][c][og*8];
            float4 b1 = *(const float4*)&w_s[1][c][og*8+4];
            float4 c0v = *(const float4*)&w_s[2][c][og*8];
            float4 c1v = *(const float4*)&w_s[2][c][og*8+4];
            float w8[3][8] = {
                {a0.x,a0.y,a0.z,a0.w, a1.x,a1.y,a1.z,a1.w},
                {b0.x,b0.y,b0.z,b0.w, b1.x,b1.y,b1.z,b1.w},
                {c0v.x,c0v.y,c0v.z,c0v.w, c1v.x,c1v.y,c1v.z,c1v.w}};
#pragma unroll
            for (int m=0;m<3;m++)
#pragma unroll
                for (int io=0;io<8;io++)
#pragma unroll
                    for (int in=0;in<4;in++)
                        acc[m][io][in] = fmaf(w8[m][io], f[in], acc[m][io][in]);
        }
    }
    const float* bias[3] = {bq, bk, bv};
    float* om[3] = {Q, K, V};
#pragma unroll
    for (int m=0;m<3;m++) {
#pragma unroll
        for (int io=0;io<8;io++) {
            int o = o0 + og*8 + io;
            float bb = bias[m][o];
            float4 w;
            w.x = acc[m][io][0]+bb; w.y = acc[m][io][1]+bb;
            w.z = acc[m][io][2]+bb; w.w = acc[m][io][3]+bb;
            *(float4*)&om[m][((size_t)b*NC + o)*NHW + n0 + nl*4] = w;
        }
    }
}

// ---------------- K2b: in-place row L2 normalize (fold 1/sqrt(hd) into Q) ----------------
// grid 512, block 256 (4 waves, one row of Q and K per wave). rows = b*NC + c (2048)
__global__ __launch_bounds__(256) void k_scale(float* __restrict__ Q, float* __restrict__ K)
{
    int wave = threadIdx.x >> 6, lane = threadIdx.x & 63;
    int row = blockIdx.x*4 + wave;
    float* qp = Q + (size_t)row*NHW;
    float* kp = K + (size_t)row*NHW;
    float4 qv[4], kv[4];
    float sq = 0.f, sk = 0.f;
#pragma unroll
    for (int t=0;t<4;t++) {
        qv[t] = ((const float4*)qp)[t*64 + lane];
        kv[t] = ((const float4*)kp)[t*64 + lane];
        sq += qv[t].x*qv[t].x + qv[t].y*qv[t].y + qv[t].z*qv[t].z + qv[t].w*qv[t].w;
        sk += kv[t].x*kv[t].x + kv[t].y*kv[t].y + kv[t].z*kv[t].z + kv[t].w*kv[t].w;
    }
#pragma unroll
    for (int off=32; off>=1; off>>=1) {
        sq += __shfl_xor(sq, off, 64);
        sk += __shfl_xor(sk, off, 64);
    }
    float fq = 0.125f / fmaxf(sqrtf(sq), EPS);   // scale = 1/sqrt(64) folded in
    float fk = 1.0f   / fmaxf(sqrtf(sk), EPS);
#pragma unroll
    for (int t=0;t<4;t++) {
        qv[t].x*=fq; qv[t].y*=fq; qv[t].z*=fq; qv[t].w*=fq;
        kv[t].x*=fk; kv[t].y*=fk; kv[t].z*=fk; kv[t].w*=fk;
        ((float4*)qp)[t*64 + lane] = qv[t];
        ((float4*)kp)[t*64 + lane] = kv[t];
    }
}

// ---------------- K3: fused attention for one instance ----------------
// grid (8 qtiles, 4 h, 8 b), block 256. Scores tiny (|s|<=8) -> exp without max-subtract.
__global__ __launch_bounds__(256,2) void k_attn(
    const float* __restrict__ Q, const float* __restrict__ K, const float* __restrict__ V,
    const float* __restrict__ masks, float* __restrict__ out, int inst, int beta)
{
    __shared__ __align__(16) float  qt_s[64][128];   // 32 KB  [c][q]
    __shared__ __align__(16) float  kv_s[64][64];    // 16 KB  K:[c][j], V:[j][c^swz]
    __shared__ __align__(16) __half pt_s[64][128];   // 16 KB  [j][q]  (total 64 KB exactly)
    int tid = threadIdx.x;
    int qt0 = blockIdx.x*128, h = blockIdx.y, b = blockIdx.z;
    int tq = tid >> 4;      // 0..15 -> q = 8*tq + iq
    int tj = tid & 15;      // 0..15 -> j = 4*tj + ij (scores) / c = 4*tj + ic (attV)
    int ch = tid >> 7, qq = tid & 127;   // q-tile staging
    int wv_ = tid >> 6, jj = tid & 63;   // k/v staging
    const float* Qg = Q + ((size_t)b*NC + h*HD)*NHW + qt0;
    const float* Kg = K + ((size_t)b*NC + h*HD)*NHW;
    const float* Vg = V + ((size_t)b*NC + h*HD)*NHW;
#pragma unroll
    for (int r=0;r<32;r++) {
        int cc = 2*r + ch;
        qt_s[cc][qq] = Qg[(size_t)cc*NHW + qq];
    }
    float acc[4][8] = {};   // [ic][iq]
    float l[8] = {};
    for (int j0=0;j0<NHW;j0+=64) {
        __syncthreads();                        // prev iter done reading kv_s/pt_s
#pragma unroll
        for (int r=0;r<16;r++) {
            int cc = 4*r + wv_;
            kv_s[cc][jj] = Kg[(size_t)cc*NHW + j0 + jj];
        }
        __syncthreads();
        float s[8][4] = {};
#pragma unroll 4
        for (int c=0;c<64;c++) {
            float4 qa = *(const float4*)&qt_s[c][8*tq];
            float4 qb = *(const float4*)&qt_s[c][8*tq+4];
            float q8[8] = {qa.x,qa.y,qa.z,qa.w, qb.x,qb.y,qb.z,qb.w};
            float4 kk = *(const float4*)&kv_s[c][4*tj];
            float k4[4] = {kk.x,kk.y,kk.z,kk.w};
#pragma unroll
            for (int iq=0;iq<8;iq++)
#pragma unroll
                for (int ij=0;ij<4;ij++)
                    s[iq][ij] = fmaf(q8[iq], k4[ij], s[iq][ij]);
        }
#pragma unroll
        for (int iq=0;iq<8;iq++)
#pragma unroll
            for (int ij=0;ij<4;ij++) {
                float p = __expf(s[iq][ij]);
                s[iq][ij] = p;
                l[iq] += p;
            }
        // p -> LDS (fp16), [j][q]
#pragma unroll
        for (int ij=0;ij<4;ij++) {
            union { uint4 u; __half2 hh[4]; } pk;
#pragma unroll
            for (int t=0;t<4;t++)
                pk.hh[t] = __halves2half2(__float2half_rn(s[2*t][ij]), __float2half_rn(s[2*t+1][ij]));
            *(uint4*)&pt_s[4*tj+ij][8*tq] = pk.u;
        }
        __syncthreads();                        // K reads + p writes done
#pragma unroll
        for (int r=0;r<16;r++) {                // V transposed + XOR swizzle
            int cc = 4*r + wv_;
            kv_s[jj][cc ^ (jj & 60)] = Vg[(size_t)cc*NHW + j0 + jj];
        }
        __syncthreads();
#pragma unroll 4
        for (int j=0;j<64;j++) {
            union { uint4 u; __half2 hh[4]; } pu;
            pu.u = *(const uint4*)&pt_s[j][8*tq];
            float pf[8];
#pragma unroll
            for (int t=0;t<4;t++){ float2 f2 = __half22float2(pu.hh[t]); pf[2*t]=f2.x; pf[2*t+1]=f2.y; }
            float4 vv = *(const float4*)&kv_s[j][(4*tj) ^ (j & 60)];
            float v4[4] = {vv.x,vv.y,vv.z,vv.w};
#pragma unroll
            for (int ic=0;ic<4;ic++)
#pragma unroll
                for (int iq=0;iq<8;iq++)
                    acc[ic][iq] = fmaf(v4[ic], pf[iq], acc[ic][iq]);
        }
    }
    // 1/l, summed across the 16 tj lanes sharing each q row
#pragma unroll
    for (int iq=0;iq<8;iq++) {
        float lv = l[iq];
        lv += __shfl_xor(lv, 1, 64);
        lv += __shfl_xor(lv, 2, 64);
        lv += __shfl_xor(lv, 4, 64);
        lv += __shfl_xor(lv, 8, 64);
        l[iq] = 1.0f / lv;
    }
    __syncthreads();
#pragma unroll
    for (int ic=0;ic<4;ic++)
#pragma unroll
        for (int iq=0;iq<8;iq++)
            qt_s[4*tj+ic][8*tq+iq] = acc[ic][iq]*l[iq];
    __syncthreads();
    const float* mk = masks + ((size_t)inst*NB + b)*NHW + qt0;
    float* op = out + ((size_t)b*NC + h*HD)*NHW + qt0;
#pragma unroll
    for (int r=0;r<32;r++) {
        int cc = 2*r + ch;
        float val = qt_s[cc][qq]*mk[qq];
        size_t oi = (size_t)cc*NHW + qq;
        if (beta) val += op[oi];
        op[oi] = val;
    }
}

extern "C" void kernel_launch(void* const* d_in, const int* in_sizes, int n_in,
                              void* d_out, int out_size, void* d_ws, size_t ws_size,
                              hipStream_t stream)
{
    const float* x      = (const float*)d_in[0];
    const float* w_inst = (const float*)d_in[1];
    const float* b_inst = (const float*)d_in[2];
    const float* wq = (const float*)d_in[3];
    const float* bq = (const float*)d_in[4];
    const float* wk = (const float*)d_in[5];
    const float* bk = (const float*)d_in[6];
    const float* wv = (const float*)d_in[7];
    const float* bv = (const float*)d_in[8];
    float* out = (float*)d_out;
    float* ws = (float*)d_ws;
    float* masks = ws;                                  // 8*8*1024
    float* Q = ws + (size_t)NI*NB*NHW;                  // 8*256*1024 each
    float* K = Q + (size_t)NB*NC*NHW;
    float* V = K + (size_t)NB*NC*NHW;

    k_masks<<<dim3(4, NB), 256, 0, stream>>>(x, w_inst, b_inst, masks);
    for (int i=0;i<NI;i++) {
        k_qkv<<<dim3(8, 4, NB), 256, 0, stream>>>(x, masks, i, wq,bq,wk,bk,wv,bv, Q, K, V);
        k_scale<<<dim3(512), 256, 0, stream>>>(Q, K);
        k_attn<<<dim3(8, NH, NB), 256, 0, stream>>>(Q, K, V, masks, out, i, (i==0)?0:1);
    }
}

// Round 2
// 1288.691 us; speedup vs baseline: 1.6908x; 1.6908x over previous
//
#include <hip/hip_runtime.h>
#include <hip/hip_fp16.h>

#define NB 8
#define NC 256
#define NHW 1024
#define NI 8
#define NH 4
#define HD 64
#define EPS 1e-12f

// ---------------- K1: instance conv + softmax over instances ----------------
// grid (4 ntiles, 8 b), block 256. masks layout [i][b][n]
__global__ __launch_bounds__(256) void k_masks(
    const float* __restrict__ x, const float* __restrict__ w_inst,
    const float* __restrict__ b_inst, float* __restrict__ masks)
{
    __shared__ float w_s[NI][NC];
    int tid = threadIdx.x;
    for (int k = tid; k < NI*NC; k += 256) ((float*)w_s)[k] = w_inst[k];
    __syncthreads();
    int b = blockIdx.y;
    int n = blockIdx.x*256 + tid;
    const float* xp = x + ((size_t)b*NC)*NHW + n;
    float acc[NI];
#pragma unroll
    for (int i=0;i<NI;i++) acc[i] = b_inst[i];
    for (int c=0;c<NC;c++) {
        float xv = xp[(size_t)c*NHW];
#pragma unroll
        for (int i=0;i<NI;i++) acc[i] = fmaf(w_s[i][c], xv, acc[i]);
    }
    float m = acc[0];
#pragma unroll
    for (int i=1;i<NI;i++) m = fmaxf(m, acc[i]);
    float ssum = 0.f;
#pragma unroll
    for (int i=0;i<NI;i++){ acc[i] = __expf(acc[i]-m); ssum += acc[i]; }
    float inv = 1.0f/ssum;
#pragma unroll
    for (int i=0;i<NI;i++) masks[((size_t)i*NB + b)*NHW + n] = acc[i]*inv;
}

// ---------------- K2: G = W*x once (mask commutes: W(x*m) = m*(Wx)) ----------------
// grid (8 ntiles, 4 otiles, 8 b), block 256. No mask, no bias here.
__global__ __launch_bounds__(256,2) void k_gemm3(
    const float* __restrict__ x,
    const float* __restrict__ wq, const float* __restrict__ wk, const float* __restrict__ wv,
    float* __restrict__ Gq, float* __restrict__ Gk, float* __restrict__ Gv)
{
    __shared__ __align__(16) float feat_s[32][128];
    __shared__ __align__(16) float w_s[3][32][68];
    int tid = threadIdx.x;
    int b = blockIdx.z, ot = blockIdx.y, nt = blockIdx.x;
    int o0 = ot*64, n0 = nt*128;
    int og = tid >> 5;
    int nl = tid & 31;
    int nn = tid & 127;
    int ch = tid >> 7;
    const float* xb = x + ((size_t)b*NC)*NHW + n0;
    float acc[3][8][4] = {};
    for (int c0 = 0; c0 < NC; c0 += 32) {
        __syncthreads();
#pragma unroll
        for (int r=0;r<16;r++) {
            int cc = 2*r + ch;
            feat_s[cc][nn] = xb[(size_t)(c0+cc)*NHW + nn];
        }
        {
            int cw = tid & 31;
#pragma unroll
            for (int r=0;r<8;r++) {
                int oo = 8*r + og;
                size_t gi = (size_t)(o0+oo)*NC + c0 + cw;
                w_s[0][cw][oo] = wq[gi];
                w_s[1][cw][oo] = wk[gi];
                w_s[2][cw][oo] = wv[gi];
            }
        }
        __syncthreads();
#pragma unroll 4
        for (int c=0;c<32;c++) {
            float4 f4 = *(const float4*)&feat_s[c][nl*4];
            float f[4] = {f4.x, f4.y, f4.z, f4.w};
            float4 a0 = *(const float4*)&w_s[0][c][og*8];
            float4 a1 = *(const float4*)&w_s[0][c][og*8+4];
            float4 b0 = *(const float4*)&w_s[1][c][og*8];
            float4 b1 = *(const float4*)&w_s[1][c][og*8+4];
            float4 c0v = *(const float4*)&w_s[2][c][og*8];
            float4 c1v = *(const float4*)&w_s[2][c][og*8+4];
            float w8[3][8] = {
                {a0.x,a0.y,a0.z,a0.w, a1.x,a1.y,a1.z,a1.w},
                {b0.x,b0.y,b0.z,b0.w, b1.x,b1.y,b1.z,b1.w},
                {c0v.x,c0v.y,c0v.z,c0v.w, c1v.x,c1v.y,c1v.z,c1v.w}};
#pragma unroll
            for (int m=0;m<3;m++)
#pragma unroll
                for (int io=0;io<8;io++)
#pragma unroll
                    for (int in=0;in<4;in++)
                        acc[m][io][in] = fmaf(w8[m][io], f[in], acc[m][io][in]);
        }
    }
    float* om[3] = {Gq, Gk, Gv};
#pragma unroll
    for (int m=0;m<3;m++) {
#pragma unroll
        for (int io=0;io<8;io++) {
            int o = o0 + og*8 + io;
            float4 w;
            w.x = acc[m][io][0]; w.y = acc[m][io][1];
            w.z = acc[m][io][2]; w.w = acc[m][io][3];
            *(float4*)&om[m][((size_t)b*NC + o)*NHW + n0 + nl*4] = w;
        }
    }
}

// ---------------- K3: per-instance row norms -> scale factors ----------------
// grid 512 blocks x 256 (wave per row). row=(b,c) in 0..2047.
// scale_q[i][row] = 0.125/max(||m_i*Gq_row + bq||,eps); scale_k = 1/max(||..||,eps)
__global__ __launch_bounds__(256) void k_norm(
    const float* __restrict__ Gq, const float* __restrict__ Gk,
    const float* __restrict__ masks,
    const float* __restrict__ bq, const float* __restrict__ bk,
    float* __restrict__ scale_q, float* __restrict__ scale_k)
{
    int wave = threadIdx.x >> 6, lane = threadIdx.x & 63;
    int row = blockIdx.x*4 + wave;
    int b = row >> 8, c = row & 255;
    const float4* gq = (const float4*)(Gq + (size_t)row*NHW);
    const float4* gk = (const float4*)(Gk + (size_t)row*NHW);
    float4 qv[4], kv[4];
#pragma unroll
    for (int t=0;t<4;t++){ qv[t] = gq[t*64+lane]; kv[t] = gk[t*64+lane]; }
    float bqv = bq[c], bkv = bk[c];
    float aq[NI], ak[NI];
#pragma unroll
    for (int i=0;i<NI;i++) {
        const float4* mp = (const float4*)(masks + ((size_t)i*NB + b)*NHW);
        float sq = 0.f, sk = 0.f;
#pragma unroll
        for (int t=0;t<4;t++) {
            float4 m = mp[t*64+lane];
            float e;
            e = m.x*qv[t].x + bqv; sq = fmaf(e,e,sq);
            e = m.y*qv[t].y + bqv; sq = fmaf(e,e,sq);
            e = m.z*qv[t].z + bqv; sq = fmaf(e,e,sq);
            e = m.w*qv[t].w + bqv; sq = fmaf(e,e,sq);
            e = m.x*kv[t].x + bkv; sk = fmaf(e,e,sk);
            e = m.y*kv[t].y + bkv; sk = fmaf(e,e,sk);
            e = m.z*kv[t].z + bkv; sk = fmaf(e,e,sk);
            e = m.w*kv[t].w + bkv; sk = fmaf(e,e,sk);
        }
        aq[i] = sq; ak[i] = sk;
    }
#pragma unroll
    for (int off=32; off>=1; off>>=1) {
#pragma unroll
        for (int i=0;i<NI;i++) {
            aq[i] += __shfl_xor(aq[i], off, 64);
            ak[i] += __shfl_xor(ak[i], off, 64);
        }
    }
    if (lane == 0) {
#pragma unroll
        for (int i=0;i<NI;i++) {
            scale_q[i*(NB*NC) + row] = 0.125f / fmaxf(sqrtf(aq[i]), EPS);
            scale_k[i*(NB*NC) + row] = 1.0f   / fmaxf(sqrtf(ak[i]), EPS);
        }
    }
}

// ---------------- K4: fused attention, all instances, one launch ----------------
// grid (16 qtiles of 64, 4 h, 8 b) = 512 blocks, block 256.
// Instance loop inside; cross-instance accumulation in registers; out written once.
__global__ __launch_bounds__(256,2) void k_attn_all(
    const float* __restrict__ Gq, const float* __restrict__ Gk, const float* __restrict__ Gv,
    const float* __restrict__ masks,
    const float* __restrict__ bq, const float* __restrict__ bk, const float* __restrict__ bv,
    const float* __restrict__ scale_q, const float* __restrict__ scale_k,
    float* __restrict__ out)
{
    __shared__ __align__(16) float  qt_s[64][68];   // [c][q]
    __shared__ __align__(16) float  kt_s[64][68];   // [c][j]
    __shared__ __align__(16) float  vt_s[64][68];   // [j][c]
    __shared__ __align__(16) __half pt_s[64][68];   // [j][q]
    __shared__ float l_s[64];
    int tid = threadIdx.x;
    int hi = tid >> 4;   // 0..15
    int lo = tid & 15;   // 0..15
    int qt0 = blockIdx.x*64, h = blockIdx.y, b = blockIdx.z;
    int c0 = h*HD;
    const size_t gbase = ((size_t)b*NC + c0)*NHW;
    float acc_tot[4][4] = {};   // [ic][iq], c=4*hi+ic, q=4*lo+iq

    for (int inst=0; inst<NI; ++inst) {
        const float* mi = masks + ((size_t)inst*NB + b)*NHW;
        const float* sqp = scale_q + inst*(NB*NC) + b*NC + c0;
        const float* skp = scale_k + inst*(NB*NC) + b*NC + c0;
        __syncthreads();   // prev inst: l_s reads + last-tile qt_s reads done
        {   // stage q tile: q = (m*Gq + bq)*scale_q
            float4 mq4 = *(const float4*)(mi + qt0 + 4*lo);
#pragma unroll
            for (int r=0;r<4;r++) {
                int c = 16*r + hi;
                float4 g = *(const float4*)(Gq + gbase + (size_t)c*NHW + qt0 + 4*lo);
                float bb = bq[c0+c], sc = sqp[c];
                float4 w;
                w.x = (g.x*mq4.x + bb)*sc;
                w.y = (g.y*mq4.y + bb)*sc;
                w.z = (g.z*mq4.z + bb)*sc;
                w.w = (g.w*mq4.w + bb)*sc;
                *(float4*)&qt_s[c][4*lo] = w;
            }
        }
        float acc[4][4] = {};
        float l[4] = {};
        for (int j0=0;j0<NHW;j0+=64) {
            __syncthreads();   // prev tile readers of kt/vt/pt done; q staged
            {   // stage k (normalized) and v tiles
                float4 mj4 = *(const float4*)(mi + j0 + 4*lo);
#pragma unroll
                for (int r=0;r<4;r++) {
                    int c = 16*r + hi;
                    float4 gk4 = *(const float4*)(Gk + gbase + (size_t)c*NHW + j0 + 4*lo);
                    float4 gv4 = *(const float4*)(Gv + gbase + (size_t)c*NHW + j0 + 4*lo);
                    float bkk = bk[c0+c], skk = skp[c], bvv = bv[c0+c];
                    float4 kk;
                    kk.x = (gk4.x*mj4.x + bkk)*skk;
                    kk.y = (gk4.y*mj4.y + bkk)*skk;
                    kk.z = (gk4.z*mj4.z + bkk)*skk;
                    kk.w = (gk4.w*mj4.w + bkk)*skk;
                    *(float4*)&kt_s[c][4*lo] = kk;
                    vt_s[4*lo+0][c] = gv4.x*mj4.x + bvv;
                    vt_s[4*lo+1][c] = gv4.y*mj4.y + bvv;
                    vt_s[4*lo+2][c] = gv4.z*mj4.z + bvv;
                    vt_s[4*lo+3][c] = gv4.w*mj4.w + bvv;
                }
            }
            __syncthreads();
            // scores: lane (hi -> q=4*hi+iq, lo -> j=4*lo+ij)
            float s[4][4] = {};
#pragma unroll 8
            for (int c=0;c<64;c++) {
                float4 qa = *(const float4*)&qt_s[c][4*hi];
                float4 ka = *(const float4*)&kt_s[c][4*lo];
                float q4[4] = {qa.x,qa.y,qa.z,qa.w};
                float k4[4] = {ka.x,ka.y,ka.z,ka.w};
#pragma unroll
                for (int iq=0;iq<4;iq++)
#pragma unroll
                    for (int ij=0;ij<4;ij++)
                        s[iq][ij] = fmaf(q4[iq], k4[ij], s[iq][ij]);
            }
#pragma unroll
            for (int iq=0;iq<4;iq++)
#pragma unroll
                for (int ij=0;ij<4;ij++) {
                    float p = __expf(s[iq][ij]);
                    s[iq][ij] = p;
                    l[iq] += p;
                }
            // p -> LDS fp16, [j][q]
#pragma unroll
            for (int ij=0;ij<4;ij++) {
                union { uint2 u; __half2 hh[2]; } pk;
                pk.hh[0] = __halves2half2(__float2half_rn(s[0][ij]), __float2half_rn(s[1][ij]));
                pk.hh[1] = __halves2half2(__float2half_rn(s[2][ij]), __float2half_rn(s[3][ij]));
                *(uint2*)&pt_s[4*lo+ij][4*hi] = pk.u;
            }
            __syncthreads();
            // PV: lane (hi -> c=4*hi+ic, lo -> q=4*lo+iq)
#pragma unroll 8
            for (int j=0;j<64;j++) {
                float4 vv = *(const float4*)&vt_s[j][4*hi];
                union { uint2 u; __half2 hh[2]; } pu;
                pu.u = *(const uint2*)&pt_s[j][4*lo];
                float2 f0 = __half22float2(pu.hh[0]);
                float2 f1 = __half22float2(pu.hh[1]);
                float pf[4] = {f0.x, f0.y, f1.x, f1.y};
                float v4[4] = {vv.x, vv.y, vv.z, vv.w};
#pragma unroll
                for (int ic=0;ic<4;ic++)
#pragma unroll
                    for (int iq=0;iq<4;iq++)
                        acc[ic][iq] = fmaf(v4[ic], pf[iq], acc[ic][iq]);
            }
        }
        // l: sum across the 16 lo-lanes sharing each q row (tid bits 0..3)
#pragma unroll
        for (int iq=0;iq<4;iq++) {
            float lv = l[iq];
            lv += __shfl_xor(lv, 1, 64);
            lv += __shfl_xor(lv, 2, 64);
            lv += __shfl_xor(lv, 4, 64);
            lv += __shfl_xor(lv, 8, 64);
            if (lo == 0) l_s[4*hi+iq] = lv;
        }
        __syncthreads();
        {   // accumulate this instance: out += (acc/l) * m[q]
            float4 mq4 = *(const float4*)(mi + qt0 + 4*lo);
            float mm[4] = {mq4.x, mq4.y, mq4.z, mq4.w};
            float inv[4];
#pragma unroll
            for (int iq=0;iq<4;iq++) inv[iq] = mm[iq] / l_s[4*lo+iq];
#pragma unroll
            for (int ic=0;ic<4;ic++)
#pragma unroll
                for (int iq=0;iq<4;iq++)
                    acc_tot[ic][iq] = fmaf(acc[ic][iq], inv[iq], acc_tot[ic][iq]);
        }
    }
    float* op = out + gbase + qt0;
#pragma unroll
    for (int ic=0;ic<4;ic++) {
        int c = 4*hi + ic;
        float4 w;
        w.x = acc_tot[ic][0]; w.y = acc_tot[ic][1];
        w.z = acc_tot[ic][2]; w.w = acc_tot[ic][3];
        *(float4*)(op + (size_t)c*NHW + 4*lo) = w;
    }
}

extern "C" void kernel_launch(void* const* d_in, const int* in_sizes, int n_in,
                              void* d_out, int out_size, void* d_ws, size_t ws_size,
                              hipStream_t stream)
{
    const float* x      = (const float*)d_in[0];
    const float* w_inst = (const float*)d_in[1];
    const float* b_inst = (const float*)d_in[2];
    const float* wq = (const float*)d_in[3];
    const float* bq = (const float*)d_in[4];
    const float* wk = (const float*)d_in[5];
    const float* bk = (const float*)d_in[6];
    const float* wv = (const float*)d_in[7];
    const float* bv = (const float*)d_in[8];
    float* out = (float*)d_out;
    float* ws = (float*)d_ws;
    float* masks = ws;                                   // 8*8*1024
    float* Gq = ws + (size_t)NI*NB*NHW;                  // 8*256*1024 each
    float* Gk = Gq + (size_t)NB*NC*NHW;
    float* Gv = Gk + (size_t)NB*NC*NHW;
    float* scale_q = Gv + (size_t)NB*NC*NHW;             // 8*2048
    float* scale_k = scale_q + (size_t)NI*NB*NC;

    k_masks<<<dim3(4, NB), 256, 0, stream>>>(x, w_inst, b_inst, masks);
    k_gemm3<<<dim3(8, 4, NB), 256, 0, stream>>>(x, wq, wk, wv, Gq, Gk, Gv);
    k_norm<<<dim3(512), 256, 0, stream>>>(Gq, Gk, masks, bq, bk, scale_q, scale_k);
    k_attn_all<<<dim3(16, NH, NB), 256, 0, stream>>>(Gq, Gk, Gv, masks,
                                                     bq, bk, bv, scale_q, scale_k, out);
}

// Round 4
// 457.849 us; speedup vs baseline: 4.7591x; 2.8147x over previous
//
#include <hip/hip_runtime.h>
#include <hip/hip_fp16.h>

#define NB 8
#define NC 256
#define NHW 1024
#define NI 8
#define NH 4
#define HD 64
#define EPS 1e-12f

typedef _Float16 f16;
typedef __attribute__((ext_vector_type(8))) _Float16 half8;
typedef __attribute__((ext_vector_type(4))) float floatx4;

union H8 { half8 h8; __half2 h2[4]; uint4 u4; };
union H4 { uint2 u2; __half2 h2[2]; };

// ---------------- K1: instance conv + softmax over instances ----------------
// grid (4 ntiles, 8 b), block 256. masks layout [i][b][n], fp32
__global__ __launch_bounds__(256) void k_masks(
    const float* __restrict__ x, const float* __restrict__ w_inst,
    const float* __restrict__ b_inst, float* __restrict__ masks)
{
    __shared__ float w_s[NI][NC];
    int tid = threadIdx.x;
    for (int k = tid; k < NI*NC; k += 256) ((float*)w_s)[k] = w_inst[k];
    __syncthreads();
    int b = blockIdx.y;
    int n = blockIdx.x*256 + tid;
    const float* xp = x + ((size_t)b*NC)*NHW + n;
    float acc[NI];
#pragma unroll
    for (int i=0;i<NI;i++) acc[i] = b_inst[i];
    for (int c=0;c<NC;c++) {
        float xv = xp[(size_t)c*NHW];
#pragma unroll
        for (int i=0;i<NI;i++) acc[i] = fmaf(w_s[i][c], xv, acc[i]);
    }
    float m = acc[0];
#pragma unroll
    for (int i=1;i<NI;i++) m = fmaxf(m, acc[i]);
    float ssum = 0.f;
#pragma unroll
    for (int i=0;i<NI;i++){ acc[i] = __expf(acc[i]-m); ssum += acc[i]; }
    float inv = 1.0f/ssum;
#pragma unroll
    for (int i=0;i<NI;i++) masks[((size_t)i*NB + b)*NHW + n] = acc[i]*inv;
}

// ---------------- K2: G = W*x once (mask commutes) -> f16 outputs ----------------
// Gqt/Gkt transposed [b][n][c] (c contiguous, for MFMA A/B frags), Gv natural [b][c][n].
// No mask, no bias here. grid (8 nt, 4 ot, 8 b), block 256.
__global__ __launch_bounds__(256,2) void k_gemm3(
    const float* __restrict__ x,
    const float* __restrict__ wq, const float* __restrict__ wk, const float* __restrict__ wv,
    f16* __restrict__ Gqt, f16* __restrict__ Gkt, f16* __restrict__ Gv)
{
    __shared__ __align__(16) float feat_s[32][128];
    __shared__ __align__(16) float w_s[3][32][68];
    int tid = threadIdx.x;
    int b = blockIdx.z, ot = blockIdx.y, nt = blockIdx.x;
    int o0 = ot*64, n0 = nt*128;
    int og = tid >> 5;
    int nl = tid & 31;
    int nn = tid & 127;
    int ch = tid >> 7;
    const float* xb = x + ((size_t)b*NC)*NHW + n0;
    float acc[3][8][4] = {};
    for (int c0 = 0; c0 < NC; c0 += 32) {
        __syncthreads();
#pragma unroll
        for (int r=0;r<16;r++) {
            int cc = 2*r + ch;
            feat_s[cc][nn] = xb[(size_t)(c0+cc)*NHW + nn];
        }
        {
            int cw = tid & 31;
#pragma unroll
            for (int r=0;r<8;r++) {
                int oo = 8*r + og;
                size_t gi = (size_t)(o0+oo)*NC + c0 + cw;
                w_s[0][cw][oo] = wq[gi];
                w_s[1][cw][oo] = wk[gi];
                w_s[2][cw][oo] = wv[gi];
            }
        }
        __syncthreads();
#pragma unroll 4
        for (int c=0;c<32;c++) {
            float4 f4 = *(const float4*)&feat_s[c][nl*4];
            float f[4] = {f4.x, f4.y, f4.z, f4.w};
            float4 a0 = *(const float4*)&w_s[0][c][og*8];
            float4 a1 = *(const float4*)&w_s[0][c][og*8+4];
            float4 b0 = *(const float4*)&w_s[1][c][og*8];
            float4 b1 = *(const float4*)&w_s[1][c][og*8+4];
            float4 c0v = *(const float4*)&w_s[2][c][og*8];
            float4 c1v = *(const float4*)&w_s[2][c][og*8+4];
            float w8[3][8] = {
                {a0.x,a0.y,a0.z,a0.w, a1.x,a1.y,a1.z,a1.w},
                {b0.x,b0.y,b0.z,b0.w, b1.x,b1.y,b1.z,b1.w},
                {c0v.x,c0v.y,c0v.z,c0v.w, c1v.x,c1v.y,c1v.z,c1v.w}};
#pragma unroll
            for (int m=0;m<3;m++)
#pragma unroll
                for (int io=0;io<8;io++)
#pragma unroll
                    for (int in=0;in<4;in++)
                        acc[m][io][in] = fmaf(w8[m][io], f[in], acc[m][io][in]);
        }
    }
    // epilogue: transposed f16 Gqt/Gkt, natural f16 Gv
#pragma unroll
    for (int in=0;in<4;in++) {
        int n = n0 + nl*4 + in;
        H8 q, k;
#pragma unroll
        for (int t=0;t<4;t++) {
            q.h2[t] = __floats2half2_rn(acc[0][2*t][in], acc[0][2*t+1][in]);
            k.h2[t] = __floats2half2_rn(acc[1][2*t][in], acc[1][2*t+1][in]);
        }
        *(uint4*)(Gqt + ((size_t)b*NHW + n)*NC + o0 + og*8) = q.u4;
        *(uint4*)(Gkt + ((size_t)b*NHW + n)*NC + o0 + og*8) = k.u4;
    }
#pragma unroll
    for (int io=0;io<8;io++) {
        int o = o0 + og*8 + io;
        H4 v;
        v.h2[0] = __floats2half2_rn(acc[2][io][0], acc[2][io][1]);
        v.h2[1] = __floats2half2_rn(acc[2][io][2], acc[2][io][3]);
        *(uint2*)(Gv + ((size_t)b*NC + o)*NHW + n0 + nl*4) = v.u2;
    }
}

// ---------------- K3: per-instance row norms over n -> scale factors ----------------
// grid (4 ct, 8 b), block 1024 (16 n-groups x 64 c).
// scale_q[i][b][c] = 0.125/max(||m_i*Gq_row + bq||,eps); scale_k analog.
__global__ __launch_bounds__(1024) void k_norm2(
    const f16* __restrict__ Gqt, const f16* __restrict__ Gkt,
    const float* __restrict__ masks,
    const float* __restrict__ bq, const float* __restrict__ bk,
    float* __restrict__ scale_q, float* __restrict__ scale_k)
{
    __shared__ float red[16][65];
    int ct = blockIdx.x, b = blockIdx.y;
    int tid = threadIdx.x;
    int g = tid >> 6;     // n-group 0..15
    int c = tid & 63;
    int cg = ct*64 + c;
    float bqv = bq[cg], bkv = bk[cg];
    const f16* gq = Gqt + (size_t)b*NHW*NC + cg;
    const f16* gk = Gkt + (size_t)b*NHW*NC + cg;
    float aq[NI] = {}, ak[NI] = {};
    for (int t = 0; t < 64; ++t) {
        int n = g*64 + t;
        float gqv = (float)gq[(size_t)n*NC];
        float gkv = (float)gk[(size_t)n*NC];
#pragma unroll
        for (int i=0;i<NI;i++) {
            float m = masks[((size_t)i*NB + b)*NHW + n];   // wave-uniform addr -> scalar load
            float e = fmaf(m, gqv, bqv); aq[i] = fmaf(e, e, aq[i]);
            e = fmaf(m, gkv, bkv);       ak[i] = fmaf(e, e, ak[i]);
        }
    }
    for (int s = 0; s < 16; ++s) {
        red[g][c] = (s < 8) ? aq[s] : ak[s-8];
        __syncthreads();
#pragma unroll
        for (int st = 8; st >= 1; st >>= 1) {
            if (g < st) red[g][c] += red[g+st][c];
            __syncthreads();
        }
        if (tid < 64) {
            float r = fmaxf(sqrtf(red[0][tid]), EPS);
            if (s < 8) scale_q[(size_t)s*(NB*NC) + b*NC + ct*64 + tid] = 0.125f / r;
            else       scale_k[(size_t)(s-8)*(NB*NC) + b*NC + ct*64 + tid] = 1.0f / r;
        }
        __syncthreads();
    }
}

// ---------------- K4: fused attention, MFMA f16, all instances ----------------
// grid 512 linear (b=bid&7 pins same-b blocks to one XCD), block 256 = 4 waves.
// q-tile 64, j-tile 64. Wave w owns scores q-rows w*16.. and PV c-rows w*16..
// Unmasked G tiles staged once per j-tile; mask/bias/scale applied on fragments (pk f16).
__global__ __launch_bounds__(256,3) void k_attn_mfma(
    const f16* __restrict__ Gqt, const f16* __restrict__ Gkt, const f16* __restrict__ Gv,
    const float* __restrict__ masks,
    const float* __restrict__ bq, const float* __restrict__ bk, const float* __restrict__ bv,
    const float* __restrict__ scale_q, const float* __restrict__ scale_k,
    float* __restrict__ out)
{
    __shared__ __align__(16) f16 gkt_s[64][72];  // [j][c], pitch 144B (odd*16B: conflict-free b128)
    __shared__ __align__(16) f16 gv_s[64][72];   // [c][j]
    __shared__ __align__(16) f16 p_s[64][72];    // [q][j]
    __shared__ __align__(16) __half mh_s[64];    // mask tile f16
    __shared__ float f_s[64];                    // m[q]/l[q] per instance

    int tid = threadIdx.x;
    int bid = blockIdx.x;
    int b = bid & 7, qt = (bid >> 3) & 15, h = bid >> 7;
    int qt0 = qt * 64, c0 = h * HD;
    int w = tid >> 6, lane = tid & 63, quad = lane >> 4, l15 = lane & 15;

    __half2 bv2 = __float2half2_rn(bv[c0 + w*16 + l15]);  // V A-frag bias (c=lane&15-indexed)

    floatx4 atot[4];
#pragma unroll
    for (int qs=0;qs<4;qs++) { atot[qs][0]=0.f; atot[qs][1]=0.f; atot[qs][2]=0.f; atot[qs][3]=0.f; }

    for (int inst = 0; inst < NI; ++inst) {
        const float* mi = masks + ((size_t)inst*NB + b)*NHW;
        // ---- per-instance: q A-frags (regs) + K-side scale/bias packed regs ----
        H8 qa[2];
        __half2 skh[2][4], bsk[2][4];
        {
            float mq = mi[qt0 + w*16 + l15];
            __half2 mq2 = __float2half2_rn(mq);
            const float* sqg = scale_q + ((size_t)inst*NB + b)*NC;
            const float* skg = scale_k + ((size_t)inst*NB + b)*NC;
#pragma unroll
            for (int ks = 0; ks < 2; ++ks) {
                int cb = c0 + ks*32 + quad*8;
                float4 s0 = *(const float4*)(sqg + cb);
                float4 s1 = *(const float4*)(sqg + cb + 4);
                float4 b0 = *(const float4*)(bq + cb);
                float4 b1 = *(const float4*)(bq + cb + 4);
                H8 g;
                g.u4 = *(const uint4*)(Gqt + ((size_t)b*NHW + qt0 + w*16 + l15)*NC + cb);
                __half2 sq2[4] = {
                    __floats2half2_rn(s0.x, s0.y), __floats2half2_rn(s0.z, s0.w),
                    __floats2half2_rn(s1.x, s1.y), __floats2half2_rn(s1.z, s1.w)};
                __half2 bs2[4] = {
                    __floats2half2_rn(b0.x*s0.x, b0.y*s0.y), __floats2half2_rn(b0.z*s0.z, b0.w*s0.w),
                    __floats2half2_rn(b1.x*s1.x, b1.y*s1.y), __floats2half2_rn(b1.z*s1.z, b1.w*s1.w)};
#pragma unroll
                for (int i = 0; i < 4; ++i)
                    qa[ks].h2[i] = __hfma2(mq2, __hmul2(g.h2[i], sq2[i]), bs2[i]);
                float4 t0 = *(const float4*)(skg + cb);
                float4 t1 = *(const float4*)(skg + cb + 4);
                float4 k0 = *(const float4*)(bk + cb);
                float4 k1 = *(const float4*)(bk + cb + 4);
                skh[ks][0] = __floats2half2_rn(t0.x, t0.y);
                skh[ks][1] = __floats2half2_rn(t0.z, t0.w);
                skh[ks][2] = __floats2half2_rn(t1.x, t1.y);
                skh[ks][3] = __floats2half2_rn(t1.z, t1.w);
                bsk[ks][0] = __floats2half2_rn(k0.x*t0.x, k0.y*t0.y);
                bsk[ks][1] = __floats2half2_rn(k0.z*t0.z, k0.w*t0.w);
                bsk[ks][2] = __floats2half2_rn(k1.x*t1.x, k1.y*t1.y);
                bsk[ks][3] = __floats2half2_rn(k1.z*t1.z, k1.w*t1.w);
            }
        }
        floatx4 acc[4];
#pragma unroll
        for (int qs=0;qs<4;qs++) { acc[qs][0]=0.f; acc[qs][1]=0.f; acc[qs][2]=0.f; acc[qs][3]=0.f; }
        float l[4] = {0.f, 0.f, 0.f, 0.f};

        for (int j0 = 0; j0 < NHW; j0 += 64) {
            __syncthreads();                       // prev-iter LDS consumers done
#pragma unroll
            for (int t = 0; t < 2; ++t) {          // stage unmasked tiles (shared by frag builds)
                int chk = tid + t*256;
                int jr = chk >> 3, cc = chk & 7;
                *(uint4*)&gkt_s[jr][cc*8] =
                    *(const uint4*)(Gkt + ((size_t)b*NHW + j0 + jr)*NC + c0 + cc*8);
                *(uint4*)&gv_s[jr][cc*8] =
                    *(const uint4*)(Gv + ((size_t)b*NC + c0 + jr)*NHW + j0 + cc*8);
            }
            if (tid < 64) mh_s[tid] = __float2half(mi[j0 + tid]);
            __syncthreads();                       // staging visible
            // ---- scores: S[q][j] = qa . K, K built on the fly ----
#pragma unroll
            for (int js = 0; js < 4; ++js) {
                __half2 mj2 = __half2half2(mh_s[js*16 + l15]);
                floatx4 sx = {0.f, 0.f, 0.f, 0.f};
#pragma unroll
                for (int ks = 0; ks < 2; ++ks) {
                    H8 g, kb;
                    g.u4 = *(const uint4*)&gkt_s[js*16 + l15][ks*32 + quad*8];
#pragma unroll
                    for (int i = 0; i < 4; ++i)
                        kb.h2[i] = __hfma2(mj2, __hmul2(g.h2[i], skh[ks][i]), bsk[ks][i]);
                    sx = __builtin_amdgcn_mfma_f32_16x16x32_f16(qa[ks].h8, kb.h8, sx, 0, 0, 0);
                }
#pragma unroll
                for (int r = 0; r < 4; ++r) {      // C layout: row q=w*16+quad*4+r, col j=js*16+l15
                    float p = __expf(sx[r]);
                    l[r] += p;
                    p_s[w*16 + quad*4 + r][js*16 + l15] = (f16)p;
                }
            }
            __syncthreads();                       // p_s complete
            // ---- PV: acc[c][q] += V . P ----
            H8 va[2];
#pragma unroll
            for (int ks = 0; ks < 2; ++ks) {
                H8 g, m8;
                g.u4  = *(const uint4*)&gv_s[w*16 + l15][ks*32 + quad*8];
                m8.u4 = *(const uint4*)&mh_s[ks*32 + quad*8];
#pragma unroll
                for (int i = 0; i < 4; ++i)
                    va[ks].h2[i] = __hfma2(m8.h2[i], g.h2[i], bv2);
            }
#pragma unroll
            for (int qs = 0; qs < 4; ++qs) {
#pragma unroll
                for (int ks = 0; ks < 2; ++ks) {
                    H8 pb;
                    pb.u4 = *(const uint4*)&p_s[qs*16 + l15][ks*32 + quad*8];
                    acc[qs] = __builtin_amdgcn_mfma_f32_16x16x32_f16(va[ks].h8, pb.h8, acc[qs], 0, 0, 0);
                }
            }
        }
        // ---- finalize instance: f[q] = m[q]/l[q]; atot += acc*f ----
        float mr[4];
#pragma unroll
        for (int r = 0; r < 4; ++r) mr[r] = mi[qt0 + w*16 + quad*4 + r];
#pragma unroll
        for (int r = 0; r < 4; ++r) {
            float lv = l[r];
            lv += __shfl_xor(lv, 1, 64);
            lv += __shfl_xor(lv, 2, 64);
            lv += __shfl_xor(lv, 4, 64);
            lv += __shfl_xor(lv, 8, 64);
            if (l15 == 0) f_s[w*16 + quad*4 + r] = mr[r] / lv;
        }
        __syncthreads();
#pragma unroll
        for (int qs = 0; qs < 4; ++qs) {
            float fl = f_s[qs*16 + l15];           // q = qs*16+l15 (D col index)
#pragma unroll
            for (int r = 0; r < 4; ++r)
                atot[qs][r] = fmaf(acc[qs][r], fl, atot[qs][r]);
        }
    }
    // ---- store: D rows c=w*16+quad*4+r, cols q=qs*16+l15 ----
    float* op = out + ((size_t)b*NC + c0)*NHW + qt0;
#pragma unroll
    for (int qs = 0; qs < 4; ++qs)
#pragma unroll
        for (int r = 0; r < 4; ++r)
            op[(size_t)(w*16 + quad*4 + r)*NHW + qs*16 + l15] = atot[qs][r];
}

extern "C" void kernel_launch(void* const* d_in, const int* in_sizes, int n_in,
                              void* d_out, int out_size, void* d_ws, size_t ws_size,
                              hipStream_t stream)
{
    const float* x      = (const float*)d_in[0];
    const float* w_inst = (const float*)d_in[1];
    const float* b_inst = (const float*)d_in[2];
    const float* wq = (const float*)d_in[3];
    const float* bq = (const float*)d_in[4];
    const float* wk = (const float*)d_in[5];
    const float* bk = (const float*)d_in[6];
    const float* wv = (const float*)d_in[7];
    const float* bv = (const float*)d_in[8];
    float* out = (float*)d_out;

    float* masks   = (float*)d_ws;                       // 8*8*1024 f32
    float* scale_q = masks + (size_t)NI*NB*NHW;          // 8*8*256
    float* scale_k = scale_q + (size_t)NI*NB*NC;
    f16*   Gqt     = (f16*)(scale_k + (size_t)NI*NB*NC); // [b][n][c] f16
    f16*   Gkt     = Gqt + (size_t)NB*NHW*NC;            // [b][n][c] f16
    f16*   Gv      = Gkt + (size_t)NB*NHW*NC;            // [b][c][n] f16

    k_masks<<<dim3(4, NB), 256, 0, stream>>>(x, w_inst, b_inst, masks);
    k_gemm3<<<dim3(8, 4, NB), 256, 0, stream>>>(x, wq, wk, wv, Gqt, Gkt, Gv);
    k_norm2<<<dim3(4, NB), 1024, 0, stream>>>(Gqt, Gkt, masks, bq, bk, scale_q, scale_k);
    k_attn_mfma<<<dim3(512), 256, 0, stream>>>(Gqt, Gkt, Gv, masks,
                                               bq, bk, bv, scale_q, scale_k, out);
}

// Round 5
// 372.034 us; speedup vs baseline: 5.8568x; 1.2307x over previous
//
#include <hip/hip_runtime.h>
#include <hip/hip_fp16.h>

#define NB 8
#define NC 256
#define NHW 1024
#define NI 8
#define NH 4
#define HD 64
#define EPS 1e-12f

typedef _Float16 f16;
typedef __attribute__((ext_vector_type(8))) _Float16 half8;
typedef __attribute__((ext_vector_type(4))) float floatx4;

union H8 { half8 h8; __half2 h2[4]; uint4 u4; };
union H4 { uint2 u2; __half2 h2[2]; };

// ---------------- K1: instance conv + softmax over instances ----------------
__global__ __launch_bounds__(256) void k_masks(
    const float* __restrict__ x, const float* __restrict__ w_inst,
    const float* __restrict__ b_inst, float* __restrict__ masks)
{
    __shared__ float w_s[NI][NC];
    int tid = threadIdx.x;
    for (int k = tid; k < NI*NC; k += 256) ((float*)w_s)[k] = w_inst[k];
    __syncthreads();
    int b = blockIdx.y;
    int n = blockIdx.x*256 + tid;
    const float* xp = x + ((size_t)b*NC)*NHW + n;
    float acc[NI];
#pragma unroll
    for (int i=0;i<NI;i++) acc[i] = b_inst[i];
    for (int c=0;c<NC;c++) {
        float xv = xp[(size_t)c*NHW];
#pragma unroll
        for (int i=0;i<NI;i++) acc[i] = fmaf(w_s[i][c], xv, acc[i]);
    }
    float m = acc[0];
#pragma unroll
    for (int i=1;i<NI;i++) m = fmaxf(m, acc[i]);
    float ssum = 0.f;
#pragma unroll
    for (int i=0;i<NI;i++){ acc[i] = __expf(acc[i]-m); ssum += acc[i]; }
    float inv = 1.0f/ssum;
#pragma unroll
    for (int i=0;i<NI;i++) masks[((size_t)i*NB + b)*NHW + n] = acc[i]*inv;
}

// ---------------- K2: G = W*x, ONE matrix per block (768 blocks = 3/CU) ----------------
// m=0: Gqt [b][n][c]; m=1: Gkt [b][n][c]; m=2: Gv [b][c][n]. All f16, no mask/bias.
__global__ __launch_bounds__(256,3) void k_gemm1(
    const float* __restrict__ x,
    const float* __restrict__ wq, const float* __restrict__ wk, const float* __restrict__ wv,
    f16* __restrict__ Gqt, f16* __restrict__ Gkt, f16* __restrict__ Gv)
{
    __shared__ __align__(16) float feat_s[32][128];
    __shared__ __align__(16) float w_s[32][68];
    int tid = threadIdx.x;
    int nt = blockIdx.x, ot = blockIdx.y;
    int m = blockIdx.z >> 3, b = blockIdx.z & 7;
    const float* wsel = (m == 0) ? wq : (m == 1) ? wk : wv;
    int o0 = ot*64, n0 = nt*128;
    int og = tid >> 5;
    int nl = tid & 31;
    int nn = tid & 127;
    int ch = tid >> 7;
    const float* xb = x + ((size_t)b*NC)*NHW + n0;
    float acc[8][4] = {};
    for (int c0 = 0; c0 < NC; c0 += 32) {
        __syncthreads();
#pragma unroll
        for (int r=0;r<16;r++) {
            int cc = 2*r + ch;
            feat_s[cc][nn] = xb[(size_t)(c0+cc)*NHW + nn];
        }
        {
            int cw = tid & 31;
#pragma unroll
            for (int r=0;r<8;r++) {
                int oo = 8*r + og;
                w_s[cw][oo] = wsel[(size_t)(o0+oo)*NC + c0 + cw];
            }
        }
        __syncthreads();
#pragma unroll 8
        for (int c=0;c<32;c++) {
            float4 f4 = *(const float4*)&feat_s[c][nl*4];
            float4 a0 = *(const float4*)&w_s[c][og*8];
            float4 a1 = *(const float4*)&w_s[c][og*8+4];
            float f[4] = {f4.x,f4.y,f4.z,f4.w};
            float w8[8] = {a0.x,a0.y,a0.z,a0.w,a1.x,a1.y,a1.z,a1.w};
#pragma unroll
            for (int io=0;io<8;io++)
#pragma unroll
                for (int in=0;in<4;in++)
                    acc[io][in] = fmaf(w8[io], f[in], acc[io][in]);
        }
    }
    if (m < 2) {
        f16* Gt = (m == 0) ? Gqt : Gkt;
#pragma unroll
        for (int in=0;in<4;in++) {
            int n = n0 + nl*4 + in;
            H8 q;
#pragma unroll
            for (int t=0;t<4;t++)
                q.h2[t] = __floats2half2_rn(acc[2*t][in], acc[2*t+1][in]);
            *(uint4*)(Gt + ((size_t)b*NHW + n)*NC + o0 + og*8) = q.u4;
        }
    } else {
#pragma unroll
        for (int io=0;io<8;io++) {
            int o = o0 + og*8 + io;
            H4 v;
            v.h2[0] = __floats2half2_rn(acc[io][0], acc[io][1]);
            v.h2[1] = __floats2half2_rn(acc[io][2], acc[io][3]);
            *(uint2*)(Gv + ((size_t)b*NC + o)*NHW + n0 + nl*4) = v.u2;
        }
    }
}

// ---------------- K3: per-instance row norms over n -> scale factors ----------------
__global__ __launch_bounds__(1024) void k_norm2(
    const f16* __restrict__ Gqt, const f16* __restrict__ Gkt,
    const float* __restrict__ masks,
    const float* __restrict__ bq, const float* __restrict__ bk,
    float* __restrict__ scale_q, float* __restrict__ scale_k)
{
    __shared__ float red[16][65];
    int ct = blockIdx.x, b = blockIdx.y;
    int tid = threadIdx.x;
    int g = tid >> 6;
    int c = tid & 63;
    int cg = ct*64 + c;
    float bqv = bq[cg], bkv = bk[cg];
    const f16* gq = Gqt + (size_t)b*NHW*NC + cg;
    const f16* gk = Gkt + (size_t)b*NHW*NC + cg;
    float aq[NI] = {}, ak[NI] = {};
    for (int t = 0; t < 64; ++t) {
        int n = g*64 + t;
        float gqv = (float)gq[(size_t)n*NC];
        float gkv = (float)gk[(size_t)n*NC];
#pragma unroll
        for (int i=0;i<NI;i++) {
            float m = masks[((size_t)i*NB + b)*NHW + n];
            float e = fmaf(m, gqv, bqv); aq[i] = fmaf(e, e, aq[i]);
            e = fmaf(m, gkv, bkv);       ak[i] = fmaf(e, e, ak[i]);
        }
    }
    for (int s = 0; s < 16; ++s) {
        red[g][c] = (s < 8) ? aq[s] : ak[s-8];
        __syncthreads();
#pragma unroll
        for (int st = 8; st >= 1; st >>= 1) {
            if (g < st) red[g][c] += red[g+st][c];
            __syncthreads();
        }
        if (tid < 64) {
            float r = fmaxf(sqrtf(red[0][tid]), EPS);
            if (s < 8) scale_q[(size_t)s*(NB*NC) + b*NC + ct*64 + tid] = 0.125f / r;
            else       scale_k[(size_t)(s-8)*(NB*NC) + b*NC + ct*64 + tid] = 1.0f / r;
        }
        __syncthreads();
    }
}

// ---------------- K4: fused attention v3 ----------------
// grid 1024 (b=bid&7 XCD pin), block 256 = 4 waves. q-tile 32, j-tile 64, inst INNER.
// Raw K/V tiles (bk cancels in softmax; sk folded into q~; bv added once at store via
// sum_i mask_i = 1). m_j applied post-MFMA on scores and absorbed into p'.
// q~ scaled x64 (f16 denormal guard), undone inside exp arg. ph double-buffered:
// one barrier per instance + one per tile stage.
#define QSC  64.0f
#define QSCI 0.015625f

__global__ __launch_bounds__(256,3) void k_attn3(
    const f16* __restrict__ Gqt, const f16* __restrict__ Gkt, const f16* __restrict__ Gv,
    const float* __restrict__ masks,
    const float* __restrict__ bq, const float* __restrict__ bv,
    const float* __restrict__ scale_q, const float* __restrict__ scale_k,
    float* __restrict__ out)
{
    __shared__ __align__(16) f16 kh_s[64][72];      // raw Gkt tile [j][c]
    __shared__ __align__(16) f16 vh_s[64][72];      // raw Gv tile  [c][j]
    __shared__ __align__(16) f16 ph_s[2][32][72];   // P' [q][j], double-buffered
    __shared__ __align__(16) f16 sqk_s[NI][64];     // (sq*sk*64) f16 per inst
    __shared__ __align__(16) f16 bqk_s[NI][64];     // bq*sq*sk*64
    __shared__ float lred_s[NI][4][32];

    int tid = threadIdx.x, bid = blockIdx.x;
    int b = bid & 7; int rr = bid >> 3; int qt = rr & 31; int h = rr >> 5;
    int qt0 = qt*32, c0 = h*HD;
    int w = tid >> 6, lane = tid & 63, quad = lane >> 4, l15 = lane & 15;

    // per-instance scale tables
#pragma unroll
    for (int t = 0; t < 2; ++t) {
        int idx = tid + t*256;
        int i = idx >> 6, c = idx & 63;
        float sq = scale_q[((size_t)i*NB + b)*NC + c0 + c];
        float sk = scale_k[((size_t)i*NB + b)*NC + c0 + c];
        float s = sq*sk*QSC;
        sqk_s[i][c] = (f16)s;
        bqk_s[i][c] = (f16)(bq[c0 + c]*s);
    }
    // raw Gq fragments (B-layout: n=q=qi*16+l15, k=c=ks*32+quad*8+t)
    H8 graw[2][2];
    const f16* gqp = Gqt + ((size_t)b*NHW + qt0)*NC + c0;
#pragma unroll
    for (int qi=0;qi<2;qi++)
#pragma unroll
        for (int ks=0;ks<2;ks++)
            graw[qi][ks].u4 = *(const uint4*)(gqp + (size_t)(qi*16 + l15)*NC + ks*32 + quad*8);
    // per-instance mask at this lane's q positions (f16 pair: qi0 lo, qi1 hi)
    __half2 mqh[NI];
#pragma unroll
    for (int i=0;i<NI;i++)
        mqh[i] = __floats2half2_rn(masks[((size_t)i*NB+b)*NHW + qt0 + l15],
                                   masks[((size_t)i*NB+b)*NHW + qt0 + 16 + l15]);

    floatx4 acc[NI][2];
#pragma unroll
    for (int i=0;i<NI;i++)
#pragma unroll
        for (int qi=0;qi<2;qi++){ acc[i][qi][0]=0.f; acc[i][qi][1]=0.f; acc[i][qi][2]=0.f; acc[i][qi][3]=0.f; }
    float l[NI][2] = {};
    __syncthreads();

    for (int j0 = 0; j0 < NHW; j0 += 64) {
        // stage raw K/V tiles (safe without leading barrier: all waves passed last
        // inst-barrier of prev tile, whose ka/va LDS reads happened before it)
#pragma unroll
        for (int t = 0; t < 2; ++t) {
            int chk = tid + t*256;
            int jr = chk >> 3, cc = chk & 7;
            *(uint4*)&kh_s[jr][cc*8] = *(const uint4*)(Gkt + ((size_t)b*NHW + j0 + jr)*NC + c0 + cc*8);
            *(uint4*)&vh_s[jr][cc*8] = *(const uint4*)(Gv + ((size_t)b*NC + c0 + jr)*NHW + j0 + cc*8);
        }
        __syncthreads();
        H8 ka[2], va[2];   // A-frags: K[m=j=w*16+l15][k=c], V[m=c=w*16+l15][k=j]
#pragma unroll
        for (int ks=0;ks<2;ks++) {
            ka[ks].u4 = *(const uint4*)&kh_s[w*16 + l15][ks*32 + quad*8];
            va[ks].u4 = *(const uint4*)&vh_s[w*16 + l15][ks*32 + quad*8];
        }
#pragma unroll
        for (int i = 0; i < NI; ++i) {
            // q~ = mq*(Gq*sqk) + bqk   (f16 packed)
            H8 qa[2][2];
            __half2 m0 = __half2half2(__low2half(mqh[i]));
            __half2 m1 = __half2half2(__high2half(mqh[i]));
#pragma unroll
            for (int ks = 0; ks < 2; ++ks) {
                H8 s8, b8;
                s8.u4 = *(const uint4*)&sqk_s[i][ks*32 + quad*8];
                b8.u4 = *(const uint4*)&bqk_s[i][ks*32 + quad*8];
#pragma unroll
                for (int t=0;t<4;t++) {
                    __half2 gs = __hmul2(graw[0][ks].h2[t], s8.h2[t]);
                    qa[0][ks].h2[t] = __hfma2(m0, gs, b8.h2[t]);
                    gs = __hmul2(graw[1][ks].h2[t], s8.h2[t]);
                    qa[1][ks].h2[t] = __hfma2(m1, gs, b8.h2[t]);
                }
            }
            // scores (swapped: A=K rows j, B=q~ cols q) -> D[j=quad*4+r][q=qi*16+l15]
            floatx4 sx0 = {0.f,0.f,0.f,0.f}, sx1 = {0.f,0.f,0.f,0.f};
#pragma unroll
            for (int ks=0;ks<2;ks++) {
                sx0 = __builtin_amdgcn_mfma_f32_16x16x32_f16(ka[ks].h8, qa[0][ks].h8, sx0, 0, 0, 0);
                sx1 = __builtin_amdgcn_mfma_f32_16x16x32_f16(ka[ks].h8, qa[1][ks].h8, sx1, 0, 0, 0);
            }
            float4 mj4 = *(const float4*)(masks + ((size_t)i*NB + b)*NHW + j0 + w*16 + quad*4);
            float mj[4] = {mj4.x, mj4.y, mj4.z, mj4.w};
            float pa[4], pc[4];
#pragma unroll
            for (int r=0;r<4;r++) {
                pa[r] = __expf(sx0[r]*(mj[r]*QSCI)); l[i][0] += pa[r];
                pc[r] = __expf(sx1[r]*(mj[r]*QSCI)); l[i][1] += pc[r];
            }
            H4 p0, p1;
            p0.h2[0] = __floats2half2_rn(pa[0]*mj[0], pa[1]*mj[1]);
            p0.h2[1] = __floats2half2_rn(pa[2]*mj[2], pa[3]*mj[3]);
            p1.h2[0] = __floats2half2_rn(pc[0]*mj[0], pc[1]*mj[1]);
            p1.h2[1] = __floats2half2_rn(pc[2]*mj[2], pc[3]*mj[3]);
            *(uint2*)&ph_s[i&1][l15][w*16 + quad*4]      = p0.u2;
            *(uint2*)&ph_s[i&1][16 + l15][w*16 + quad*4] = p1.u2;
            __syncthreads();   // ph complete (double-buffer: 1 barrier/inst)
            // PV: acc[c][q] += V . P'
#pragma unroll
            for (int ks = 0; ks < 2; ++ks) {
                H8 pf;
                pf.u4 = *(const uint4*)&ph_s[i&1][l15][ks*32 + quad*8];
                acc[i][0] = __builtin_amdgcn_mfma_f32_16x16x32_f16(va[ks].h8, pf.h8, acc[i][0], 0, 0, 0);
                pf.u4 = *(const uint4*)&ph_s[i&1][16 + l15][ks*32 + quad*8];
                acc[i][1] = __builtin_amdgcn_mfma_f32_16x16x32_f16(va[ks].h8, pf.h8, acc[i][1], 0, 0, 0);
            }
        }
    }
    // reduce l across quads (in-wave) then waves (LDS)
#pragma unroll
    for (int i = 0; i < NI; ++i)
#pragma unroll
        for (int qi=0;qi<2;qi++) {
            float lv = l[i][qi];
            lv += __shfl_xor(lv, 16, 64);
            lv += __shfl_xor(lv, 32, 64);
            if (lane < 16) lred_s[i][w][qi*16 + lane] = lv;
        }
    __syncthreads();
    float4 bv4 = *(const float4*)(bv + c0 + w*16 + quad*4);
    float bvr[4] = {bv4.x, bv4.y, bv4.z, bv4.w};
    float ot[2][4] = {};
#pragma unroll
    for (int i=0;i<NI;i++)
#pragma unroll
        for (int qi=0;qi<2;qi++) {
            float lt = lred_s[i][0][qi*16+l15] + lred_s[i][1][qi*16+l15]
                     + lred_s[i][2][qi*16+l15] + lred_s[i][3][qi*16+l15];
            float mqf = masks[((size_t)i*NB + b)*NHW + qt0 + qi*16 + l15];
            float f = mqf / lt;
#pragma unroll
            for (int r=0;r<4;r++) ot[qi][r] = fmaf(acc[i][qi][r], f, ot[qi][r]);
        }
    float* op = out + ((size_t)b*NC + c0)*NHW + qt0;
#pragma unroll
    for (int qi=0;qi<2;qi++)
#pragma unroll
        for (int r=0;r<4;r++)
            op[(size_t)(w*16 + quad*4 + r)*NHW + qi*16 + l15] = ot[qi][r] + bvr[r];
}

extern "C" void kernel_launch(void* const* d_in, const int* in_sizes, int n_in,
                              void* d_out, int out_size, void* d_ws, size_t ws_size,
                              hipStream_t stream)
{
    const float* x      = (const float*)d_in[0];
    const float* w_inst = (const float*)d_in[1];
    const float* b_inst = (const float*)d_in[2];
    const float* wq = (const float*)d_in[3];
    const float* bq = (const float*)d_in[4];
    const float* wk = (const float*)d_in[5];
    const float* bk = (const float*)d_in[6];
    const float* wv = (const float*)d_in[7];
    const float* bv = (const float*)d_in[8];
    float* out = (float*)d_out;

    float* masks   = (float*)d_ws;                       // 8*8*1024 f32
    float* scale_q = masks + (size_t)NI*NB*NHW;          // 8*8*256
    float* scale_k = scale_q + (size_t)NI*NB*NC;
    f16*   Gqt     = (f16*)(scale_k + (size_t)NI*NB*NC); // [b][n][c] f16
    f16*   Gkt     = Gqt + (size_t)NB*NHW*NC;            // [b][n][c] f16
    f16*   Gv      = Gkt + (size_t)NB*NHW*NC;            // [b][c][n] f16

    k_masks<<<dim3(4, NB), 256, 0, stream>>>(x, w_inst, b_inst, masks);
    k_gemm1<<<dim3(8, 4, 24), 256, 0, stream>>>(x, wq, wk, wv, Gqt, Gkt, Gv);
    k_norm2<<<dim3(4, NB), 1024, 0, stream>>>(Gqt, Gkt, masks, bq, bk, scale_q, scale_k);
    k_attn3<<<dim3(1024), 256, 0, stream>>>(Gqt, Gkt, Gv, masks,
                                            bq, bv, scale_q, scale_k, out);
}

// Round 6
// 282.156 us; speedup vs baseline: 7.7224x; 1.3185x over previous
//
#include <hip/hip_runtime.h>
#include <hip/hip_fp16.h>

#define NB 8
#define NC 256
#define NHW 1024
#define NI 8
#define NH 4
#define HD 64
#define EPS 1e-12f
#define QSC  64.0f
#define QSCI 0.015625f

typedef _Float16 f16;
typedef __attribute__((ext_vector_type(8))) _Float16 half8;
typedef __attribute__((ext_vector_type(4))) float floatx4;

union H8 { half8 h8; __half2 h2[4]; uint4 u4; };
union H4 { uint2 u2; __half2 h2[2]; };

// ---------------- K1a: mask logits, partial over c-chunks (128 blocks) ----------------
__global__ __launch_bounds__(256) void k_mask_part(
    const float* __restrict__ x, const float* __restrict__ w_inst,
    float* __restrict__ part_m)
{
    __shared__ float w_s[NI][64];
    int nt = blockIdx.x, b = blockIdx.y, cc = blockIdx.z;
    int tid = threadIdx.x;
#pragma unroll
    for (int t = 0; t < 2; ++t) {
        int e = tid + t*256;
        w_s[e >> 6][e & 63] = w_inst[(e >> 6)*NC + cc*64 + (e & 63)];
    }
    __syncthreads();
    int n = nt*256 + tid;
    const float* xp = x + ((size_t)(b*NC + cc*64))*NHW + n;
    float acc[NI] = {};
    for (int c = 0; c < 64; ++c) {
        float xv = xp[(size_t)c*NHW];
#pragma unroll
        for (int i = 0; i < NI; ++i) acc[i] = fmaf(w_s[i][c], xv, acc[i]);
    }
#pragma unroll
    for (int i = 0; i < NI; ++i)
        part_m[((size_t)(cc*NI + i)*NB + b)*NHW + n] = acc[i];
}

// ---------------- K1b: combine + softmax over instances ----------------
__global__ __launch_bounds__(256) void k_mask_comb(
    const float* __restrict__ part_m, const float* __restrict__ b_inst,
    float* __restrict__ masks)
{
    int nt = blockIdx.x, b = blockIdx.y;
    int n = nt*256 + threadIdx.x;
    float a[NI];
#pragma unroll
    for (int i = 0; i < NI; ++i) {
        float s = b_inst[i];
#pragma unroll
        for (int cc = 0; cc < 4; ++cc)
            s += part_m[((size_t)(cc*NI + i)*NB + b)*NHW + n];
        a[i] = s;
    }
    float m = a[0];
#pragma unroll
    for (int i = 1; i < NI; ++i) m = fmaxf(m, a[i]);
    float ssum = 0.f;
#pragma unroll
    for (int i = 0; i < NI; ++i) { a[i] = __expf(a[i]-m); ssum += a[i]; }
    float inv = 1.0f/ssum;
#pragma unroll
    for (int i = 0; i < NI; ++i) masks[((size_t)i*NB + b)*NHW + n] = a[i]*inv;
}

// ---------------- K2: G = W*x, one matrix per block (768 blocks = 3/CU) ----------------
__global__ __launch_bounds__(256,3) void k_gemm1(
    const float* __restrict__ x,
    const float* __restrict__ wq, const float* __restrict__ wk, const float* __restrict__ wv,
    f16* __restrict__ Gqt, f16* __restrict__ Gkt, f16* __restrict__ Gv)
{
    __shared__ __align__(16) float feat_s[32][128];
    __shared__ __align__(16) float w_s[32][68];
    int tid = threadIdx.x;
    int nt = blockIdx.x, ot = blockIdx.y;
    int m = blockIdx.z >> 3, b = blockIdx.z & 7;
    const float* wsel = (m == 0) ? wq : (m == 1) ? wk : wv;
    int o0 = ot*64, n0 = nt*128;
    int og = tid >> 5;
    int nl = tid & 31;
    int nn = tid & 127;
    int ch = tid >> 7;
    const float* xb = x + ((size_t)b*NC)*NHW + n0;
    float acc[8][4] = {};
    for (int c0 = 0; c0 < NC; c0 += 32) {
        __syncthreads();
#pragma unroll
        for (int r=0;r<16;r++) {
            int cc = 2*r + ch;
            feat_s[cc][nn] = xb[(size_t)(c0+cc)*NHW + nn];
        }
        {
            int cw = tid & 31;
#pragma unroll
            for (int r=0;r<8;r++) {
                int oo = 8*r + og;
                w_s[cw][oo] = wsel[(size_t)(o0+oo)*NC + c0 + cw];
            }
        }
        __syncthreads();
#pragma unroll 8
        for (int c=0;c<32;c++) {
            float4 f4 = *(const float4*)&feat_s[c][nl*4];
            float4 a0 = *(const float4*)&w_s[c][og*8];
            float4 a1 = *(const float4*)&w_s[c][og*8+4];
            float f[4] = {f4.x,f4.y,f4.z,f4.w};
            float w8[8] = {a0.x,a0.y,a0.z,a0.w,a1.x,a1.y,a1.z,a1.w};
#pragma unroll
            for (int io=0;io<8;io++)
#pragma unroll
                for (int in=0;in<4;in++)
                    acc[io][in] = fmaf(w8[io], f[in], acc[io][in]);
        }
    }
    if (m < 2) {
        f16* Gt = (m == 0) ? Gqt : Gkt;
#pragma unroll
        for (int in=0;in<4;in++) {
            int n = n0 + nl*4 + in;
            H8 q;
#pragma unroll
            for (int t=0;t<4;t++)
                q.h2[t] = __floats2half2_rn(acc[2*t][in], acc[2*t+1][in]);
            *(uint4*)(Gt + ((size_t)b*NHW + n)*NC + o0 + og*8) = q.u4;
        }
    } else {
#pragma unroll
        for (int io=0;io<8;io++) {
            int o = o0 + og*8 + io;
            H4 v;
            v.h2[0] = __floats2half2_rn(acc[io][0], acc[io][1]);
            v.h2[1] = __floats2half2_rn(acc[io][2], acc[io][3]);
            *(uint2*)(Gv + ((size_t)b*NC + o)*NHW + n0 + nl*4) = v.u2;
        }
    }
}

// ---------------- K3a: norm partials over n-chunks (128 blocks) ----------------
__global__ __launch_bounds__(256) void k_norm_part(
    const f16* __restrict__ Gqt, const f16* __restrict__ Gkt,
    const float* __restrict__ masks,
    const float* __restrict__ bq, const float* __restrict__ bk,
    float* __restrict__ part_nq, float* __restrict__ part_nk)
{
    __shared__ float m_s[NI][64];
    int nc = blockIdx.x, b = blockIdx.y;
    int c = threadIdx.x;
    int n0 = nc*64;
#pragma unroll
    for (int t = 0; t < 2; ++t) {
        int e = c + t*256;
        m_s[e >> 6][e & 63] = masks[((size_t)(e >> 6)*NB + b)*NHW + n0 + (e & 63)];
    }
    __syncthreads();
    float bqv = bq[c], bkv = bk[c];
    const f16* gq = Gqt + ((size_t)b*NHW + n0)*NC + c;
    const f16* gk = Gkt + ((size_t)b*NHW + n0)*NC + c;
    float aq[NI] = {}, ak[NI] = {};
    for (int t = 0; t < 64; ++t) {
        float g1 = (float)gq[(size_t)t*NC];
        float g2 = (float)gk[(size_t)t*NC];
#pragma unroll
        for (int i = 0; i < NI; ++i) {
            float mm = m_s[i][t];
            float e = fmaf(mm, g1, bqv); aq[i] = fmaf(e, e, aq[i]);
            e = fmaf(mm, g2, bkv);       ak[i] = fmaf(e, e, ak[i]);
        }
    }
#pragma unroll
    for (int i = 0; i < NI; ++i) {
        part_nq[((size_t)(nc*NI + i)*NB + b)*NC + c] = aq[i];
        part_nk[((size_t)(nc*NI + i)*NB + b)*NC + c] = ak[i];
    }
}

// ---------------- K3b: finalize scales ----------------
__global__ __launch_bounds__(256) void k_norm_fin(
    const float* __restrict__ part_nq, const float* __restrict__ part_nk,
    float* __restrict__ scale_q, float* __restrict__ scale_k)
{
    int b = blockIdx.x, c = threadIdx.x;
#pragma unroll
    for (int i = 0; i < NI; ++i) {
        float sq = 0.f, sk = 0.f;
#pragma unroll
        for (int nc = 0; nc < 16; ++nc) {
            sq += part_nq[((size_t)(nc*NI + i)*NB + b)*NC + c];
            sk += part_nk[((size_t)(nc*NI + i)*NB + b)*NC + c];
        }
        scale_q[((size_t)i*NB + b)*NC + c] = 0.125f / fmaxf(sqrtf(sq), EPS);
        scale_k[((size_t)i*NB + b)*NC + c] = 1.0f   / fmaxf(sqrtf(sk), EPS);
    }
}

// ---------------- K4: fused attention v4 — wave owns 2 instances ----------------
// grid 1024 (b=bid&7 XCD pin), block 256 = 4 waves. q-tile 32, j-tile 64.
// Wave w handles instances {2w, 2w+1} over the FULL 64c x 32q tile: P' transpose is
// same-wave LDS (no per-instance barrier; 2 barriers/tile). q~ frags hoisted per block.
__global__ __launch_bounds__(256,3) void k_attn4(
    const f16* __restrict__ Gqt, const f16* __restrict__ Gkt, const f16* __restrict__ Gv,
    const float* __restrict__ masks,
    const float* __restrict__ bq, const float* __restrict__ bv,
    const float* __restrict__ scale_q, const float* __restrict__ scale_k,
    float* __restrict__ out)
{
    __shared__ __align__(16) f16 kh_s[64][72];       // raw Gkt tile [j][c]
    __shared__ __align__(16) f16 vh_s[64][72];       // raw Gv tile  [c][j]
    __shared__ __align__(16) f16 ph_s[4][32][72];    // per-wave P' [q][j]
    __shared__ __align__(16) float mi_s[NI][64];     // mask tile, all instances
    __shared__ __align__(16) float red_s[64][36];    // cross-wave out reduce

    int tid = threadIdx.x, bid = blockIdx.x;
    int b = bid & 7, qt = (bid >> 3) & 31, h = bid >> 8;
    int qt0 = qt*32, c0 = h*HD;
    int w = tid >> 6, lane = tid & 63, quad = lane >> 4, l15 = lane & 15;
    int i0 = 2*w;

    // ---- hoisted: raw Gq B-frags ----
    H8 graw[2][2];
    const f16* gqp = Gqt + ((size_t)b*NHW + qt0)*NC + c0;
#pragma unroll
    for (int qi = 0; qi < 2; ++qi)
#pragma unroll
        for (int ks = 0; ks < 2; ++ks)
            graw[qi][ks].u4 = *(const uint4*)(gqp + (size_t)(qi*16 + l15)*NC + ks*32 + quad*8);

    // ---- hoisted: per-instance q~ frags (mask+bias+scales folded, x64) ----
    float mqf[2][2];
#pragma unroll
    for (int ii = 0; ii < 2; ++ii)
#pragma unroll
        for (int qi = 0; qi < 2; ++qi)
            mqf[ii][qi] = masks[((size_t)(i0+ii)*NB + b)*NHW + qt0 + qi*16 + l15];

    H8 qa[2][2][2];   // [ii][qi][ks]
#pragma unroll
    for (int ks = 0; ks < 2; ++ks) {
        int cb = c0 + ks*32 + quad*8;
        float4 bq0 = *(const float4*)(bq + cb);
        float4 bq1 = *(const float4*)(bq + cb + 4);
#pragma unroll
        for (int ii = 0; ii < 2; ++ii) {
            int inst = i0 + ii;
            const float* sqg = scale_q + ((size_t)inst*NB + b)*NC;
            const float* skg = scale_k + ((size_t)inst*NB + b)*NC;
            float4 s0 = *(const float4*)(sqg + cb);
            float4 s1 = *(const float4*)(sqg + cb + 4);
            float4 t0 = *(const float4*)(skg + cb);
            float4 t1 = *(const float4*)(skg + cb + 4);
            float ss[8] = {s0.x*t0.x*QSC, s0.y*t0.y*QSC, s0.z*t0.z*QSC, s0.w*t0.w*QSC,
                           s1.x*t1.x*QSC, s1.y*t1.y*QSC, s1.z*t1.z*QSC, s1.w*t1.w*QSC};
            float bb[8] = {bq0.x*ss[0], bq0.y*ss[1], bq0.z*ss[2], bq0.w*ss[3],
                           bq1.x*ss[4], bq1.y*ss[5], bq1.z*ss[6], bq1.w*ss[7]};
            __half2 sh[4], bh[4];
#pragma unroll
            for (int t = 0; t < 4; ++t) {
                sh[t] = __floats2half2_rn(ss[2*t], ss[2*t+1]);
                bh[t] = __floats2half2_rn(bb[2*t], bb[2*t+1]);
            }
#pragma unroll
            for (int qi = 0; qi < 2; ++qi) {
                __half2 mq2 = __float2half2_rn(mqf[ii][qi]);
#pragma unroll
                for (int t = 0; t < 4; ++t)
                    qa[ii][qi][ks].h2[t] = __hfma2(mq2, __hmul2(graw[qi][ks].h2[t], sh[t]), bh[t]);
            }
        }
    }

    floatx4 acc[2][4][2];   // [ii][cm][qi]
#pragma unroll
    for (int ii=0;ii<2;ii++)
#pragma unroll
        for (int cm=0;cm<4;cm++)
#pragma unroll
            for (int qi=0;qi<2;qi++) { acc[ii][cm][qi][0]=0.f; acc[ii][cm][qi][1]=0.f;
                                       acc[ii][cm][qi][2]=0.f; acc[ii][cm][qi][3]=0.f; }
    float l[2][2] = {};

    for (int j0 = 0; j0 < NHW; j0 += 64) {
        __syncthreads();   // prev-tile consumers done
#pragma unroll
        for (int t = 0; t < 2; ++t) {
            int chk = tid + t*256;
            int jr = chk >> 3, cc = chk & 7;
            *(uint4*)&kh_s[jr][cc*8] = *(const uint4*)(Gkt + ((size_t)b*NHW + j0 + jr)*NC + c0 + cc*8);
            *(uint4*)&vh_s[jr][cc*8] = *(const uint4*)(Gv + ((size_t)b*NC + c0 + jr)*NHW + j0 + cc*8);
        }
        {
            int i = tid >> 5, jj = (tid & 31)*2;
            *(float2*)&mi_s[i][jj] = *(const float2*)(masks + ((size_t)i*NB + b)*NHW + j0 + jj);
        }
        __syncthreads();   // staging visible

#pragma unroll
        for (int ii = 0; ii < 2; ++ii) {
            int inst = i0 + ii;
            // scores (A=K rows j, B=q~ cols q) -> D[j=jm*16+quad*4+r][q=qi*16+l15]
#pragma unroll
            for (int jm = 0; jm < 4; ++jm) {
                floatx4 s0 = {0.f,0.f,0.f,0.f}, s1 = {0.f,0.f,0.f,0.f};
#pragma unroll
                for (int ks = 0; ks < 2; ++ks) {
                    H8 ka; ka.u4 = *(const uint4*)&kh_s[jm*16 + l15][ks*32 + quad*8];
                    s0 = __builtin_amdgcn_mfma_f32_16x16x32_f16(ka.h8, qa[ii][0][ks].h8, s0, 0, 0, 0);
                    s1 = __builtin_amdgcn_mfma_f32_16x16x32_f16(ka.h8, qa[ii][1][ks].h8, s1, 0, 0, 0);
                }
                float4 mj4 = *(const float4*)&mi_s[inst][jm*16 + quad*4];
                float mj[4] = {mj4.x, mj4.y, mj4.z, mj4.w};
                float p0[4], p1[4];
#pragma unroll
                for (int r = 0; r < 4; ++r) {
                    float e0 = __expf(s0[r]*(mj[r]*QSCI)); l[ii][0] += e0; p0[r] = e0*mj[r];
                    float e1 = __expf(s1[r]*(mj[r]*QSCI)); l[ii][1] += e1; p1[r] = e1*mj[r];
                }
                H4 pk0, pk1;
                pk0.h2[0] = __floats2half2_rn(p0[0], p0[1]);
                pk0.h2[1] = __floats2half2_rn(p0[2], p0[3]);
                pk1.h2[0] = __floats2half2_rn(p1[0], p1[1]);
                pk1.h2[1] = __floats2half2_rn(p1[2], p1[3]);
                *(uint2*)&ph_s[w][l15][jm*16 + quad*4]      = pk0.u2;   // qi=0 rows
                *(uint2*)&ph_s[w][16 + l15][jm*16 + quad*4] = pk1.u2;   // qi=1 rows
            }
            // PV (same-wave ph read-back; compiler inserts lgkmcnt waits)
#pragma unroll
            for (int cm = 0; cm < 4; ++cm)
#pragma unroll
                for (int ksj = 0; ksj < 2; ++ksj) {
                    H8 va; va.u4 = *(const uint4*)&vh_s[cm*16 + l15][ksj*32 + quad*8];
                    H8 pb;
                    pb.u4 = *(const uint4*)&ph_s[w][l15][ksj*32 + quad*8];
                    acc[ii][cm][0] = __builtin_amdgcn_mfma_f32_16x16x32_f16(va.h8, pb.h8, acc[ii][cm][0], 0, 0, 0);
                    pb.u4 = *(const uint4*)&ph_s[w][16 + l15][ksj*32 + quad*8];
                    acc[ii][cm][1] = __builtin_amdgcn_mfma_f32_16x16x32_f16(va.h8, pb.h8, acc[ii][cm][1], 0, 0, 0);
                }
        }
    }

    // ---- l: in-wave reduce over quads (lane bits 4,5) ----
    float f[2][2];
#pragma unroll
    for (int ii = 0; ii < 2; ++ii)
#pragma unroll
        for (int qi = 0; qi < 2; ++qi) {
            float lv = l[ii][qi];
            lv += __shfl_xor(lv, 16, 64);
            lv += __shfl_xor(lv, 32, 64);
            f[ii][qi] = mqf[ii][qi] / lv;
        }
    // ---- cross-wave reduce of sum_i f_i*acc_i ----
#pragma unroll
    for (int wp = 0; wp < 4; ++wp) {
        if (w == wp) {
#pragma unroll
            for (int cm = 0; cm < 4; ++cm)
#pragma unroll
                for (int qi = 0; qi < 2; ++qi)
#pragma unroll
                    for (int r = 0; r < 4; ++r) {
                        int cr = cm*16 + quad*4 + r, qc = qi*16 + l15;
                        float val = f[0][qi]*acc[0][cm][qi][r] + f[1][qi]*acc[1][cm][qi][r];
                        if (wp == 0) red_s[cr][qc] = val;
                        else         red_s[cr][qc] += val;
                    }
        }
        __syncthreads();
    }
    // ---- coalesced store + bv (sum_i mask_i = 1) ----
    int cc2 = tid >> 2, qg = (tid & 3)*8;
    float bvv = bv[c0 + cc2];
    float* op = out + ((size_t)(b*NC + c0 + cc2))*NHW + qt0;
#pragma unroll
    for (int t = 0; t < 2; ++t) {
        float4 v = *(const float4*)&red_s[cc2][qg + t*4];
        v.x += bvv; v.y += bvv; v.z += bvv; v.w += bvv;
        *(float4*)(op + qg + t*4) = v;
    }
}

extern "C" void kernel_launch(void* const* d_in, const int* in_sizes, int n_in,
                              void* d_out, int out_size, void* d_ws, size_t ws_size,
                              hipStream_t stream)
{
    const float* x      = (const float*)d_in[0];
    const float* w_inst = (const float*)d_in[1];
    const float* b_inst = (const float*)d_in[2];
    const float* wq = (const float*)d_in[3];
    const float* bq = (const float*)d_in[4];
    const float* wk = (const float*)d_in[5];
    const float* bk = (const float*)d_in[6];
    const float* wv = (const float*)d_in[7];
    const float* bv = (const float*)d_in[8];
    float* out = (float*)d_out;

    float* masks   = (float*)d_ws;                        // 8*8*1024 f32
    float* scale_q = masks + (size_t)NI*NB*NHW;           // 8*8*256
    float* scale_k = scale_q + (size_t)NI*NB*NC;
    f16*   Gqt     = (f16*)(scale_k + (size_t)NI*NB*NC);  // [b][n][c] f16
    f16*   Gkt     = Gqt + (size_t)NB*NHW*NC;             // [b][n][c] f16
    f16*   Gv      = Gkt + (size_t)NB*NHW*NC;             // [b][c][n] f16
    float* part_m  = (float*)(Gv + (size_t)NB*NC*NHW);    // 4*8*8*1024
    float* part_nq = part_m + (size_t)4*NI*NB*NHW;        // 16*8*8*256
    float* part_nk = part_nq + (size_t)16*NI*NB*NC;

    k_mask_part<<<dim3(4, NB, 4), 256, 0, stream>>>(x, w_inst, part_m);
    k_mask_comb<<<dim3(4, NB), 256, 0, stream>>>(part_m, b_inst, masks);
    k_gemm1<<<dim3(8, 4, 24), 256, 0, stream>>>(x, wq, wk, wv, Gqt, Gkt, Gv);
    k_norm_part<<<dim3(16, NB), 256, 0, stream>>>(Gqt, Gkt, masks, bq, bk, part_nq, part_nk);
    k_norm_fin<<<dim3(NB), 256, 0, stream>>>(part_nq, part_nk, scale_q, scale_k);
    k_attn4<<<dim3(1024), 256, 0, stream>>>(Gqt, Gkt, Gv, masks, bq, bv,
                                            scale_q, scale_k, out);
}